// Round 2
// baseline (307.755 us; speedup 1.0000x reference)
//
#include <hip/hip_runtime.h>
#include <stdint.h>

#define N_CL    8
#define C_IN    862
#define SEQ     720
#define SEQP    768            // K padded to 12 x 64
#define PRED    336
#define BATCH   64
#define BK      64
#define NCH     (SEQP / BK)    // 12 chunks
#define XBSTRIDE ((size_t)C_IN * SEQ)   // x stride between batches (elements)

typedef __attribute__((ext_vector_type(8))) __bf16 bf16x8;
typedef __attribute__((ext_vector_type(4))) float  floatx4;

__device__ __forceinline__ void async16(const void* g, void* l) {
  __builtin_amdgcn_global_load_lds(
      (__attribute__((address_space(1))) unsigned int*)(uintptr_t)g,
      (__attribute__((address_space(3))) unsigned int*)l,
      16, 0, 0);
}

// ---- Kernel 1: W fp32 [8][336][720] -> bf16 [8][336][768] (zero-padded K) ----
__global__ void wconv_kernel(const float* __restrict__ W, __bf16* __restrict__ Wb) {
  const int row = blockIdx.x;                 // 0 .. 8*336-1
  const float* src = W + (size_t)row * SEQ;
  __bf16* dst = Wb + (size_t)row * SEQP;
  for (int s = threadIdx.x; s < SEQP; s += blockDim.x) {
    float v = (s < SEQ) ? src[s] : 0.0f;
    dst[s] = (__bf16)v;
  }
}

// ---- Kernel 2: per-channel GEMM. Block = 256 thr (4 waves), one channel. ----
// Wave tiling: each wave computes ALL 4 m-tiles (64 batches) x a 5-tile n-strip
// (wave 3 takes a 6th tile: 21 = 3*5 + 6). B frag feeds 4 MFMAs, A frag 5-6.
// LDS A: 64 rows x 64 bf16 (128 B/row), 16B-granule XOR-swizzled -> 8192 B
// LDS B: 336 rows x 64 bf16 (128 B/row), 16B-granule XOR-swizzled -> 43008 B
// Total 51200 B -> 3 blocks/CU.
#define A_BYTES 8192
#define B_BYTES 43008

__global__ __launch_bounds__(256, 3) void clin_kernel(
    const float* __restrict__ x, const int* __restrict__ clusters,
    const __bf16* __restrict__ Wb, const float* __restrict__ bias,
    float* __restrict__ out) {
  __shared__ __attribute__((aligned(128))) unsigned char smem[A_BYTES + B_BYTES];
  unsigned char* As = smem;
  unsigned char* Bs = smem + A_BYTES;

  const int c    = blockIdx.x;
  const int cl   = clusters[c];
  const int tid  = threadIdx.x;
  const int wave = tid >> 6;
  const int lane = tid & 63;
  const int q    = lane >> 4;     // quad 0..3
  const int ln   = lane & 15;     // lane-in-quad 0..15
  const int m7   = ln & 7;        // read-side swizzle mask

  const float*  xc = x  + (size_t)c * SEQ;
  const __bf16* wc = Wb + (size_t)cl * PRED * SEQP;

  floatx4 acc[4][5];
  floatx4 accx[4];                // wave 3's extra n-tile (tile 20)
#pragma unroll
  for (int mt = 0; mt < 4; ++mt) {
#pragma unroll
    for (int t = 0; t < 5; ++t) acc[mt][t] = (floatx4){0.f, 0.f, 0.f, 0.f};
    accx[mt] = (floatx4){0.f, 0.f, 0.f, 0.f};
  }

  // --- A staging mapping (manual fp32->bf16): thread covers 16 k of one row ---
  const int ar  = tid >> 2;              // batch row 0..63
  const int ag0 = (tid & 3) << 1;        // even logical granule (granules ag0, ag0+1)
  const int am  = ar & 7;                // write-side swizzle mask (== ln&7 at read)
  const uint32_t aoff0 = (uint32_t)ar * 128 + (((ag0    ) ^ am) << 4);
  const uint32_t aoff1 = (uint32_t)ar * 128 + (((ag0 + 1) ^ am) << 4);
  const float* asrc = xc + (size_t)ar * XBSTRIDE;

  // --- B staging mapping (async16): 42 issues of 1024 B per chunk ---
  const int bB_r  = lane >> 3;
  const int bB_pg = lane & 7;

  const int nb = wave * 5;               // this wave's first n-tile

  for (int chunk = 0; chunk < NCH; ++chunk) {
    const int k0 = chunk * BK;

    // ---- stage B tile: 336 rows x 128 B ----
    for (int i = wave; i < 42; i += 4) {
      int r  = (i << 3) + bB_r;                 // p-row 0..335
      int lg = bB_pg ^ (r & 7);
      async16(wc + (size_t)r * SEQP + k0 + (lg << 3), Bs + i * 1024);
    }

    // ---- stage A tile: 64 rows x 64 k, fp32 -> bf16, swizzled ds_write ----
    if (k0 + BK <= SEQ) {
      const float* s = asrc + k0 + (ag0 << 3);
      floatx4 f0 = *(const floatx4*)(s);
      floatx4 f1 = *(const floatx4*)(s + 4);
      floatx4 f2 = *(const floatx4*)(s + 8);
      floatx4 f3 = *(const floatx4*)(s + 12);
      bf16x8 h0, h1;
      h0[0] = (__bf16)f0[0]; h0[1] = (__bf16)f0[1];
      h0[2] = (__bf16)f0[2]; h0[3] = (__bf16)f0[3];
      h0[4] = (__bf16)f1[0]; h0[5] = (__bf16)f1[1];
      h0[6] = (__bf16)f1[2]; h0[7] = (__bf16)f1[3];
      h1[0] = (__bf16)f2[0]; h1[1] = (__bf16)f2[1];
      h1[2] = (__bf16)f2[2]; h1[3] = (__bf16)f2[3];
      h1[4] = (__bf16)f3[0]; h1[5] = (__bf16)f3[1];
      h1[6] = (__bf16)f3[2]; h1[7] = (__bf16)f3[3];
      *(bf16x8*)(As + aoff0) = h0;
      *(bf16x8*)(As + aoff1) = h1;
    } else {
      // K tail (only last chunk): zero-fill past s=720
      float tmp[16];
#pragma unroll
      for (int j = 0; j < 16; ++j) {
        int k = k0 + (ag0 << 3) + j;
        tmp[j] = (k < SEQ) ? asrc[k] : 0.0f;
      }
      bf16x8 h0, h1;
#pragma unroll
      for (int j = 0; j < 8; ++j) { h0[j] = (__bf16)tmp[j]; h1[j] = (__bf16)tmp[8 + j]; }
      *(bf16x8*)(As + aoff0) = h0;
      *(bf16x8*)(As + aoff1) = h1;
    }
    __syncthreads();

    // ---- compute ----
#pragma unroll
    for (int kk = 0; kk < BK; kk += 32) {
      const int gA = (kk >> 3) + q;             // logical granule 0..7
      bf16x8 a[4];
#pragma unroll
      for (int mt = 0; mt < 4; ++mt)
        a[mt] = *(const bf16x8*)(As + ((mt << 4) + ln) * 128 + ((gA ^ m7) << 4));
#pragma unroll
      for (int t = 0; t < 5; ++t) {
        int n = ((nb + t) << 4) + ln;           // n&7 == ln&7
        bf16x8 b = *(const bf16x8*)(Bs + n * 128 + ((gA ^ m7) << 4));
#pragma unroll
        for (int mt = 0; mt < 4; ++mt)
          acc[mt][t] = __builtin_amdgcn_mfma_f32_16x16x32_bf16(a[mt], b, acc[mt][t], 0, 0, 0);
      }
      if (wave == 3) {                          // extra tile 20 (wave-uniform branch)
        int n = (20 << 4) + ln;
        bf16x8 b = *(const bf16x8*)(Bs + n * 128 + ((gA ^ m7) << 4));
#pragma unroll
        for (int mt = 0; mt < 4; ++mt)
          accx[mt] = __builtin_amdgcn_mfma_f32_16x16x32_bf16(a[mt], b, accx[mt], 0, 0, 0);
      }
    }
    __syncthreads();
  }

  // ---- epilogue: bias add + store. C/D layout: col=ln, row=q*4+reg ----
  const float* bc = bias + cl * PRED;
#pragma unroll
  for (int t = 0; t < 5; ++t) {
    int p = ((nb + t) << 4) + ln;
    float bv = bc[p];
#pragma unroll
    for (int mt = 0; mt < 4; ++mt) {
#pragma unroll
      for (int r = 0; r < 4; ++r) {
        int brow = (mt << 4) + (q << 2) + r;
        out[((size_t)brow * C_IN + c) * PRED + p] = acc[mt][t][r] + bv;
      }
    }
  }
  if (wave == 3) {
    int p = (20 << 4) + ln;
    float bv = bc[p];
#pragma unroll
    for (int mt = 0; mt < 4; ++mt) {
#pragma unroll
      for (int r = 0; r < 4; ++r) {
        int brow = (mt << 4) + (q << 2) + r;
        out[((size_t)brow * C_IN + c) * PRED + p] = accx[mt][r] + bv;
      }
    }
  }
}

extern "C" void kernel_launch(void* const* d_in, const int* in_sizes, int n_in,
                              void* d_out, int out_size, void* d_ws, size_t ws_size,
                              hipStream_t stream) {
  const float* x   = (const float*)d_in[0];
  const int*   cls = (const int*)d_in[1];
  const float* W   = (const float*)d_in[2];
  const float* b   = (const float*)d_in[3];
  float* out = (float*)d_out;
  __bf16* Wb = (__bf16*)d_ws;   // 8*336*768*2 = 4,128,768 B

  hipLaunchKernelGGL(wconv_kernel, dim3(N_CL * PRED), dim3(256), 0, stream, W, Wb);
  hipLaunchKernelGGL(clin_kernel, dim3(C_IN), dim3(256), 0, stream,
                     x, cls, Wb, b, out);
}

// Round 3
// 302.276 us; speedup vs baseline: 1.0181x; 1.0181x over previous
//
#include <hip/hip_runtime.h>
#include <stdint.h>

#define N_CL    8
#define C_IN    862
#define SEQ     720
#define SEQP    768            // K padded to 12 x 64
#define PRED    336
#define BK      64
#define NCH     12
#define XBSTRIDE ((size_t)C_IN * SEQ)   // x stride between batches (elements)

#define H0_ROWS 176            // n-half 0: 11 tiles
#define H1_ROWS 160            // n-half 1: 10 tiles
#define A_BYTES 8192           // 64 rows x 64 bf16 (128 B/row), XOR-swizzled
#define B_BYTES (H0_ROWS * 128)  // 22528 (max of the two halves)
#define BUF_BYTES (A_BYTES + B_BYTES)   // 30720; x2 = 61440 <= 64 KB static LDS

typedef __attribute__((ext_vector_type(8))) __bf16 bf16x8;
typedef __attribute__((ext_vector_type(4))) float  floatx4;

__device__ __forceinline__ void async16(const void* g, void* l) {
  __builtin_amdgcn_global_load_lds(
      (__attribute__((address_space(1))) unsigned int*)(uintptr_t)g,
      (__attribute__((address_space(3))) unsigned int*)l,
      16, 0, 0);
}

// ---- Kernel 1: W fp32 [8][336][720] -> bf16 [8][336][768] (zero-padded K) ----
__global__ void wconv_kernel(const float* __restrict__ W, __bf16* __restrict__ Wb) {
  const int row = blockIdx.x;                 // 0 .. 8*336-1
  const float* src = W + (size_t)row * SEQ;
  __bf16* dst = Wb + (size_t)row * SEQP;
  for (int s = threadIdx.x; s < SEQP; s += blockDim.x) {
    float v = (s < SEQ) ? src[s] : 0.0f;
    dst[s] = (__bf16)v;
  }
}

// ---- Kernel 2: block = (channel, n-half). 256 thr (4 waves). Double-buffered.
// Pipeline per chunk k: [barrier: buf[k&1] ready] -> prefetch A(k+1) to regs +
// issue B(k+1) asyncs into buf[~k&1] -> compute buf[k&1] -> cvt+ds_write A(k+1).
// Wave-tiling: every wave does all 4 m-tiles x cyclic n-tiles (w, w+4, w+8).
__global__ __launch_bounds__(256, 2) void clin_kernel(
    const float* __restrict__ x, const int* __restrict__ clusters,
    const __bf16* __restrict__ Wb, const float* __restrict__ bias,
    float* __restrict__ out) {
  __shared__ __attribute__((aligned(128))) unsigned char smem[2 * BUF_BYTES];

  const int bid  = blockIdx.x;
  const int c    = bid >> 1;
  const int half = bid & 1;
  const int nrows = half ? H1_ROWS : H0_ROWS;   // B rows this block stages
  const int ntl   = half ? 10 : 11;             // n-tiles this block computes
  const int prow0 = half * H0_ROWS;             // first p-row

  const int cl   = clusters[c];
  const int tid  = threadIdx.x;
  const int wave = tid >> 6;
  const int lane = tid & 63;
  const int q    = lane >> 4;     // quad 0..3
  const int ln   = lane & 15;     // lane-in-quad 0..15
  const int m7   = ln & 7;        // read-side swizzle mask

  const float*  xc = x  + (size_t)c * SEQ;
  const __bf16* wc = Wb + (size_t)cl * PRED * SEQP + (size_t)prow0 * SEQP;

  floatx4 acc[4][3];              // 4 m-tiles x up-to-3 cyclic n-tiles
#pragma unroll
  for (int mt = 0; mt < 4; ++mt)
#pragma unroll
    for (int t = 0; t < 3; ++t) acc[mt][t] = (floatx4){0.f, 0.f, 0.f, 0.f};

  // --- A staging mapping: thread covers 16 k of one batch row ---
  const int ar  = tid >> 2;               // batch row 0..63
  const int ag0 = (tid & 3) << 1;         // even logical granule (ag0, ag0+1)
  const int am  = ar & 7;                 // write-side swizzle (== ln&7 at read)
  const uint32_t aoff0 = (uint32_t)ar * 128 + (((ag0    ) ^ am) << 4);
  const uint32_t aoff1 = (uint32_t)ar * 128 + (((ag0 + 1) ^ am) << 4);
  const float* asrc = xc + (size_t)ar * XBSTRIDE;

  // --- B staging mapping (async16): 1024 B per issue = 8 rows x 8 granules ---
  const int bB_r  = lane >> 3;
  const int bB_pg = lane & 7;
  const int nBi   = nrows >> 3;           // 22 or 20 issues per chunk

  // ---------------- prologue: stage chunk 0 into buf 0 ----------------
  {
    unsigned char* As = smem;
    unsigned char* Bs = smem + A_BYTES;
    for (int i = wave; i < nBi; i += 4) {
      int r  = (i << 3) + bB_r;
      int lg = bB_pg ^ (r & 7);
      async16(wc + (size_t)r * SEQP + (lg << 3), Bs + i * 1024);
    }
    const float* s = asrc + (ag0 << 3);
    floatx4 f0 = *(const floatx4*)(s);
    floatx4 f1 = *(const floatx4*)(s + 4);
    floatx4 f2 = *(const floatx4*)(s + 8);
    floatx4 f3 = *(const floatx4*)(s + 12);
    bf16x8 h0, h1;
#pragma unroll
    for (int j = 0; j < 4; ++j) {
      h0[j]   = (__bf16)f0[j]; h0[4+j] = (__bf16)f1[j];
      h1[j]   = (__bf16)f2[j]; h1[4+j] = (__bf16)f3[j];
    }
    *(bf16x8*)(As + aoff0) = h0;
    *(bf16x8*)(As + aoff1) = h1;
  }

  // ---------------- main pipelined loop ----------------
  for (int k = 0; k < NCH; ++k) {
    __syncthreads();                       // buf[k&1] ready (drains asyncs+writes)
    unsigned char* As  = smem + (k & 1) * BUF_BYTES;
    unsigned char* Bs  = As + A_BYTES;
    unsigned char* Asn = smem + ((k + 1) & 1) * BUF_BYTES;
    unsigned char* Bsn = Asn + A_BYTES;

    // -- prefetch chunk k+1: A to regs (issue first), B via async16 --
    floatx4 f0, f1, f2, f3;
    bool have_next = (k + 1 < NCH);
    if (have_next) {
      const int k0n = (k + 1) * BK;
      if (k0n + BK <= SEQ) {
        const float* s = asrc + k0n + (ag0 << 3);
        f0 = *(const floatx4*)(s);
        f1 = *(const floatx4*)(s + 4);
        f2 = *(const floatx4*)(s + 8);
        f3 = *(const floatx4*)(s + 12);
      } else {                             // K tail: zero-fill past s=720
        float tmp[16];
#pragma unroll
        for (int j = 0; j < 16; ++j) {
          int kk2 = k0n + (ag0 << 3) + j;
          tmp[j] = (kk2 < SEQ) ? asrc[kk2] : 0.0f;
        }
        f0 = (floatx4){tmp[0], tmp[1], tmp[2], tmp[3]};
        f1 = (floatx4){tmp[4], tmp[5], tmp[6], tmp[7]};
        f2 = (floatx4){tmp[8], tmp[9], tmp[10], tmp[11]};
        f3 = (floatx4){tmp[12], tmp[13], tmp[14], tmp[15]};
      }
      const int k0b = (k + 1) * BK;
      for (int i = wave; i < nBi; i += 4) {
        int r  = (i << 3) + bB_r;
        int lg = bB_pg ^ (r & 7);
        async16(wc + (size_t)r * SEQP + k0b + (lg << 3), Bsn + i * 1024);
      }
    }

    // -- compute chunk k from buf[k&1] --
#pragma unroll
    for (int kk = 0; kk < BK; kk += 32) {
      const int gA = (kk >> 3) + q;        // logical granule 0..7
      bf16x8 a[4];
#pragma unroll
      for (int mt = 0; mt < 4; ++mt)
        a[mt] = *(const bf16x8*)(As + ((mt << 4) + ln) * 128 + ((gA ^ m7) << 4));
#pragma unroll
      for (int t = 0; t < 3; ++t) {
        int tl = wave + (t << 2);          // cyclic n-tile assignment
        if (tl < ntl) {
          bf16x8 b = *(const bf16x8*)(Bs + ((tl << 4) + ln) * 128 + ((gA ^ m7) << 4));
#pragma unroll
          for (int mt = 0; mt < 4; ++mt)
            acc[mt][t] = __builtin_amdgcn_mfma_f32_16x16x32_bf16(a[mt], b, acc[mt][t], 0, 0, 0);
        }
      }
    }

    // -- finish A(k+1): cvt + swizzled ds_write into buf[~k&1] --
    if (have_next) {
      bf16x8 h0, h1;
#pragma unroll
      for (int j = 0; j < 4; ++j) {
        h0[j]   = (__bf16)f0[j]; h0[4+j] = (__bf16)f1[j];
        h1[j]   = (__bf16)f2[j]; h1[4+j] = (__bf16)f3[j];
      }
      *(bf16x8*)(Asn + aoff0) = h0;
      *(bf16x8*)(Asn + aoff1) = h1;
    }
  }

  // ---- epilogue: bias add + store. C/D layout: col=ln, row=q*4+reg ----
  const float* bc = bias + cl * PRED + prow0;
#pragma unroll
  for (int t = 0; t < 3; ++t) {
    int tl = wave + (t << 2);
    if (tl < ntl) {
      int p  = (tl << 4) + ln;             // local p within this half
      float bv = bc[p];
      int pg = prow0 + p;                  // global p
#pragma unroll
      for (int mt = 0; mt < 4; ++mt) {
#pragma unroll
        for (int r = 0; r < 4; ++r) {
          int brow = (mt << 4) + (q << 2) + r;
          out[((size_t)brow * C_IN + c) * PRED + pg] = acc[mt][t][r] + bv;
        }
      }
    }
  }
}

extern "C" void kernel_launch(void* const* d_in, const int* in_sizes, int n_in,
                              void* d_out, int out_size, void* d_ws, size_t ws_size,
                              hipStream_t stream) {
  const float* x   = (const float*)d_in[0];
  const int*   cls = (const int*)d_in[1];
  const float* W   = (const float*)d_in[2];
  const float* b   = (const float*)d_in[3];
  float* out = (float*)d_out;
  __bf16* Wb = (__bf16*)d_ws;   // 8*336*768*2 = 4,128,768 B

  hipLaunchKernelGGL(wconv_kernel, dim3(N_CL * PRED), dim3(256), 0, stream, W, Wb);
  hipLaunchKernelGGL(clin_kernel, dim3(C_IN * 2), dim3(256), 0, stream,
                     x, cls, Wb, b, out);
}

// Round 4
// 292.184 us; speedup vs baseline: 1.0533x; 1.0345x over previous
//
#include <hip/hip_runtime.h>
#include <stdint.h>

#define N_CL    8
#define C_IN    862
#define SEQ     720
#define SEQP    768            // K padded to 12 x 64
#define PRED    336
#define BK      64
#define NCH     12
#define MBLOCKS 435            // >= max sum_g ceil(C_g/2) = (862+8)/2

#define WB_BYTES 4128768       // 8*336*768*2
// meta (ints) after Wb: ch_perm[862], cstart[9], bstart[9]

typedef __attribute__((ext_vector_type(8)))  __bf16 bf16x8;
typedef __attribute__((ext_vector_type(4)))  float  floatx4;
typedef __attribute__((ext_vector_type(16))) float  floatx16;

__device__ __forceinline__ void async16(const void* g, void* l) {
  __builtin_amdgcn_global_load_lds(
      (__attribute__((address_space(1))) unsigned int*)(uintptr_t)g,
      (__attribute__((address_space(3))) unsigned int*)l,
      16, 0, 0);
}

// ---- Kernel 0: group channels by cluster (deterministic stable order) ----
__global__ void prep_kernel(const int* __restrict__ clusters, int* __restrict__ meta) {
  __shared__ int cls_s[C_IN];
  __shared__ int cnt[N_CL];
  __shared__ int cst[N_CL + 1], bst[N_CL + 1];
  const int t = threadIdx.x;             // blockDim = 1024
  if (t < N_CL) cnt[t] = 0;
  __syncthreads();
  int cl = -1;
  if (t < C_IN) { cl = clusters[t]; cls_s[t] = cl; }
  __syncthreads();
  int rank = 0;
  if (t < C_IN) {
    for (int j = 0; j < t; ++j) rank += (cls_s[j] == cl) ? 1 : 0;
    atomicAdd(&cnt[cl], 1);
  }
  __syncthreads();
  if (t == 0) {
    int a = 0, b = 0;
    for (int g = 0; g < N_CL; ++g) {
      cst[g] = a; bst[g] = b;
      a += cnt[g]; b += (cnt[g] + 1) >> 1;
    }
    cst[N_CL] = a; bst[N_CL] = b;
  }
  __syncthreads();
  if (t < C_IN) meta[cst[cl] + rank] = t;
  if (t < N_CL + 1) { meta[C_IN + t] = cst[t]; meta[C_IN + 9 + t] = bst[t]; }
}

// ---- Kernel 1: W fp32 [8][336][720] -> bf16 [8][336][768] (zero-padded K) ----
__global__ void wconv_kernel(const float* __restrict__ W, __bf16* __restrict__ Wb) {
  const int row = blockIdx.x;            // 0 .. 8*336-1
  const float* src = W + (size_t)row * SEQ;
  __bf16* dst = Wb + (size_t)row * SEQP;
  for (int s = threadIdx.x; s < SEQP; s += blockDim.x) {
    float v = (s < SEQ) ? src[s] : 0.0f;
    dst[s] = (__bf16)v;
  }
}

// ---- Kernel 2: cluster-grouped GEMM. Block = 512 thr (8 waves). ----
// M=128 (2 channels of one cluster), N=336 (10 full 32-tiles + one 16-wide),
// K chunks of 64. mfma_f32_32x32x16_bf16, wave tile = 2 m-tiles x 3 n-tiles.
// A: reg-prefetch (dist 1) -> cvt bf16 -> LDS, single-buffered.
// B: global_load_lds (bf16 Wb), single-buffered.
#define A_BYTES 16384          // 128 rows x 128 B, 16B-granule XOR-swizzled
#define B_BYTES 43008          // 336 rows x 128 B, 16B-granule XOR-swizzled

__global__ __launch_bounds__(512, 2) void clin_kernel(
    const float* __restrict__ x, const int* __restrict__ meta,
    const __bf16* __restrict__ Wb, const float* __restrict__ bias,
    float* __restrict__ out) {
  __shared__ __attribute__((aligned(128))) unsigned char smem[A_BYTES + B_BYTES];
  unsigned char* As = smem;
  unsigned char* Bs = smem + A_BYTES;

  const int* cstart = meta + C_IN;
  const int* bstart = meta + C_IN + 9;
  const int bid = blockIdx.x;
  if (bid >= bstart[N_CL]) return;       // padded grid tail (uniform, pre-barrier)

  int g = 0;
#pragma unroll
  for (int i = 1; i < N_CL; ++i) g = (bid >= bstart[i]) ? i : g;
  const int lb     = bid - bstart[g];
  const int nch_g  = cstart[g + 1] - cstart[g];
  const int ch0    = meta[cstart[g] + (lb << 1)];
  const bool v1    = ((lb << 1) + 1) < nch_g;
  const int ch1    = v1 ? meta[cstart[g] + (lb << 1) + 1] : ch0;

  const int t    = threadIdx.x;
  const int wave = t >> 6;
  const int lane = t & 63;
  const int col  = lane & 31;
  const int half = lane >> 5;
  const int nt0  = wave >> 1;            // n-tiles {nt0, nt0+4, nt0+8}
  const int mt0  = (wave & 1) << 1;      // m-tiles {mt0, mt0+1}

  const __bf16* wc = Wb + (size_t)g * PRED * SEQP;

  floatx16 acc[2][3];
#pragma unroll
  for (int mi = 0; mi < 2; ++mi)
#pragma unroll
    for (int s = 0; s < 3; ++s)
#pragma unroll
      for (int r = 0; r < 16; ++r) acc[mi][s][r] = 0.0f;

  // --- A staging: thread covers 16 k of one of 128 rows ---
  const int rt    = t >> 2;              // block-local m row
  const int batch = rt & 63;
  const int chA   = (rt >> 6) ? ch1 : ch0;
  const float* srcp = x + ((size_t)batch * C_IN + chA) * SEQ;
  const int koff  = (t & 3) << 4;        // k offset within chunk
  const int bg0   = (t & 3) << 1;        // bf16 granule pair
  const uint32_t aw0 = (uint32_t)rt * 128 + (((bg0    ) ^ (rt & 7)) << 4);
  const uint32_t aw1 = (uint32_t)rt * 128 + (((bg0 + 1) ^ (rt & 7)) << 4);

  floatx4 f0, f1, f2, f3;
  // prologue: A(0) -> regs -> LDS, issue B(0)
  {
    const float* s = srcp + koff;
    f0 = *(const floatx4*)(s);     f1 = *(const floatx4*)(s + 4);
    f2 = *(const floatx4*)(s + 8); f3 = *(const floatx4*)(s + 12);
    bf16x8 h0, h1;
#pragma unroll
    for (int j = 0; j < 4; ++j) {
      h0[j] = (__bf16)f0[j]; h0[4 + j] = (__bf16)f1[j];
      h1[j] = (__bf16)f2[j]; h1[4 + j] = (__bf16)f3[j];
    }
    *(bf16x8*)(As + aw0) = h0;
    *(bf16x8*)(As + aw1) = h1;
    for (int i = wave; i < 42; i += 8) {
      int r  = (i << 3) + (lane >> 3);
      int lg = (lane & 7) ^ (r & 7);
      async16(wc + (size_t)r * SEQP + (lg << 3), Bs + i * 1024);
    }
  }

  for (int k = 0; k < NCH; ++k) {
    __syncthreads();                     // drains B(k) asyncs + A(k) ds_writes

    // prefetch A(k+1) -> regs (no wait; lands during compute)
    const bool have_next = (k + 1 < NCH);
    if (have_next) {
      const int kb = (k + 1) * BK + koff;
      if (kb + 16 <= SEQ) {
        const float* s = srcp + kb;
        f0 = *(const floatx4*)(s);     f1 = *(const floatx4*)(s + 4);
        f2 = *(const floatx4*)(s + 8); f3 = *(const floatx4*)(s + 12);
      } else {
        f0 = (floatx4){0.f,0.f,0.f,0.f}; f1 = f0; f2 = f0; f3 = f0;
      }
    }

    // compute chunk k
#pragma unroll
    for (int ks = 0; ks < 4; ++ks) {
      const int g2 = (ks << 1) + half;   // logical 16B granule 0..7
      const int r0 = (mt0 << 5) + col;
      const int r1 = r0 + 32;
      bf16x8 a0 = *(const bf16x8*)(As + r0 * 128 + ((g2 ^ (r0 & 7)) << 4));
      bf16x8 a1 = *(const bf16x8*)(As + r1 * 128 + ((g2 ^ (r1 & 7)) << 4));
#pragma unroll
      for (int s = 0; s < 3; ++s) {
        const int tl = nt0 + (s << 2);
        if (tl <= 10) {
          const int cc = (tl == 10) ? (col & 15) : col;   // 16-wide last tile
          const int rb = (tl << 5) + cc;
          bf16x8 b = *(const bf16x8*)(Bs + rb * 128 + ((g2 ^ (rb & 7)) << 4));
          acc[0][s] = __builtin_amdgcn_mfma_f32_32x32x16_bf16(a0, b, acc[0][s], 0, 0, 0);
          acc[1][s] = __builtin_amdgcn_mfma_f32_32x32x16_bf16(a1, b, acc[1][s], 0, 0, 0);
        }
      }
    }

    __syncthreads();                     // all LDS reads of chunk k done

    if (have_next) {
      // issue B(k+1) first (max latency), then cvt+write A(k+1)
      const int k0b = (k + 1) * BK;
      for (int i = wave; i < 42; i += 8) {
        int r  = (i << 3) + (lane >> 3);
        int lg = (lane & 7) ^ (r & 7);
        async16(wc + (size_t)r * SEQP + k0b + (lg << 3), Bs + i * 1024);
      }
      bf16x8 h0, h1;
#pragma unroll
      for (int j = 0; j < 4; ++j) {
        h0[j] = (__bf16)f0[j]; h0[4 + j] = (__bf16)f1[j];
        h1[j] = (__bf16)f2[j]; h1[4 + j] = (__bf16)f3[j];
      }
      *(bf16x8*)(As + aw0) = h0;
      *(bf16x8*)(As + aw1) = h1;
    }
  }

  // ---- epilogue. C/D 32x32: col=lane&31, row=(reg&3)+8*(reg>>2)+4*half ----
  const bool cvalid = (wave & 1) ? v1 : true;
  const int  chO    = (wave & 1) ? ch1 : ch0;
  if (cvalid) {
    const float* bc = bias + g * PRED;
#pragma unroll
    for (int s = 0; s < 3; ++s) {
      const int tl = nt0 + (s << 2);
      if (tl <= 10) {
        const int p = (tl << 5) + col;
        if (p < PRED) {
          const float bv = bc[p];
#pragma unroll
          for (int mi = 0; mi < 2; ++mi) {
            const int mt = mt0 + mi;
#pragma unroll
            for (int r = 0; r < 16; ++r) {
              const int m  = (r & 3) + ((r >> 2) << 3) + (half << 2);
              const int bb = ((mt << 5) + m) & 63;     // batch index
              out[((size_t)bb * C_IN + chO) * PRED + p] = acc[mi][s][r] + bv;
            }
          }
        }
      }
    }
  }
}

extern "C" void kernel_launch(void* const* d_in, const int* in_sizes, int n_in,
                              void* d_out, int out_size, void* d_ws, size_t ws_size,
                              hipStream_t stream) {
  const float* x   = (const float*)d_in[0];
  const int*   cls = (const int*)d_in[1];
  const float* W   = (const float*)d_in[2];
  const float* b   = (const float*)d_in[3];
  float* out = (float*)d_out;
  __bf16* Wb = (__bf16*)d_ws;
  int* meta  = (int*)((unsigned char*)d_ws + WB_BYTES);   // 880 ints

  hipLaunchKernelGGL(prep_kernel,  dim3(1),            dim3(1024), 0, stream, cls, meta);
  hipLaunchKernelGGL(wconv_kernel, dim3(N_CL * PRED),  dim3(256),  0, stream, W, Wb);
  hipLaunchKernelGGL(clin_kernel,  dim3(MBLOCKS),      dim3(512),  0, stream,
                     x, meta, Wb, b, out);
}